// Round 20
// baseline (298.697 us; speedup 1.0000x reference)
//
#include <hip/hip_runtime.h>
#include <float.h>

// Best-measured variants (r19) + r20 change: screen code-split 2 -> 4
// (1024 blocks = 4 blocks/CU -> 8 waves/SIMD; A-reuse per MFMA unchanged).
// Replica-f32 semantics (bit-exact vs np reference) unchanged throughout.
//
// Workspace (float slots). ushort arrays occupy size/2 slots.
//   out1 : ws[0 .. 8388608)
//     xh  = ws+0        ushort[1048576]  -> slots [0,       524288)
//     xl  = ws+524288   ushort[1048576]  -> slots [524288, 1048576)
//     ch  = ws+1048576  ushort[524288]   -> slots [1048576,1310720)
//     cl  = ws+1310720  ushort[524288]   -> slots [1310720,1572864)
//     pm1 = ws+1572864  [4][16384] f32   -> [1572864,1638400)
//     pi1 = ws+1638400  [4][16384] i32   -> [1638400,1703936)
//     pm2 = ws+1703936  [4][16384] f32   -> [1703936,1769472) < 8388608
//   out2 : ws+8388608   [16][64][64][64]
//   flat : ws+12582912  [16384][64]
//   sx   : ws+13631488  [16384]
//   sc   : ws+13647872  [8192]
//   count: ws+13656064  (int)
//   list : ws+13656320  (int[16384])
//   qbest: ws+13672704  (u64[16384] = 32768 slots, ends 13705472)
//   wp2  : ws+13705472  [32768]  packed conv2 weights
//   wp3  : ws+13738240  [65536]  packed conv3 weights (ends 13803776)

#define TAU_ACC 2e-6f   // acc-domain gap threshold (= TAU/2, TAU=4e-6 in g)

typedef __attribute__((ext_vector_type(8))) short s16x8;
typedef __attribute__((ext_vector_type(4))) float f32x4;
typedef unsigned short ushort_t;
typedef unsigned long long u64;

static __device__ __forceinline__ unsigned short f2bf(float f) {
    unsigned u = __float_as_uint(f);
    u = (u + 0x7fffu + ((u >> 16) & 1u)) >> 16;    // RN-even; no NaN in this data
    return (unsigned short)u;
}
static __device__ __forceinline__ float bf2f(unsigned short h) {
    return __uint_as_float(((unsigned)h) << 16);
}

// ---------------- weight repack: w[oc][ic][kh][kw] -> wpack[(ic*16+t)*OC + oc]
__global__ __launch_bounds__(256) void wpack_kernel(const float* __restrict__ w2,
                                                    const float* __restrict__ w3,
                                                    float* __restrict__ wp2,
                                                    float* __restrict__ wp3) {
    int i = blockIdx.x * 256 + threadIdx.x;        // 98304
    if (i < 32768) {                               // w2: [64][32][4][4]
        int oc = i >> 9, rem = i & 511;
        int ic = rem >> 4, t = rem & 15;
        wp2[(ic * 16 + t) * 64 + oc] = w2[i];
    } else if (i < 98304) {                        // w3: [64][64][4][4]
        int j = i - 32768;
        int oc = j >> 10, rem = j & 1023;
        int ic = rem >> 4, t = rem & 15;
        wp3[(ic * 16 + t) * 64 + oc] = w3[j];
    }
}

// ---------------- conv1: x[16,3,256,256] -> relu -> out1[16,32,128,128], k4 s2 p1
__global__ __launch_bounds__(256) void conv1_kernel(const float* __restrict__ in,
                                                    const float* __restrict__ w,   // [32][3][4][4]
                                                    const float* __restrict__ bias,// [32]
                                                    float* __restrict__ out) {
    int p = blockIdx.x * 256 + threadIdx.x;        // 262144
    int ow = p & 127, oh = (p >> 7) & 127, bb = p >> 14;
    int oc0 = blockIdx.y * 16;
    float taps[48];                                 // [ic][kh][kw]
    for (int ic = 0; ic < 3; ++ic) {
        const float* ip = in + (bb * 3 + ic) * 65536;
        #pragma unroll
        for (int kh = 0; kh < 4; ++kh) {
            int ih = oh * 2 - 1 + kh;
            #pragma unroll
            for (int kw = 0; kw < 4; ++kw) {
                int iw = ow * 2 - 1 + kw;
                bool ok = ((unsigned)ih < 256u) && ((unsigned)iw < 256u);
                taps[ic * 16 + kh * 4 + kw] = ok ? ip[ih * 256 + iw] : 0.0f;
            }
        }
    }
    float* op = out + bb * (32 * 16384) + oh * 128 + ow;
    for (int oc = oc0; oc < oc0 + 16; ++oc) {
        float acc = 0.0f;
        const float* wp = w + oc * 48;             // wave-uniform
        #pragma unroll
        for (int t = 0; t < 48; ++t) acc = __fmaf_rn(taps[t], wp[t], acc);
        acc = __fadd_rn(acc, bias[oc]);
        op[oc * 16384] = fmaxf(acc, 0.0f);
    }
}

// ---------------- conv2: 1 row x 16 oc, packed weights (contiguous s_loads)
__global__ __launch_bounds__(256, 4) void conv2_kernel(const float* __restrict__ in,
                                                       const float* __restrict__ wp, // packed [ic*16+t][64]
                                                       const float* __restrict__ bias,
                                                       float* __restrict__ out) {
    int p = blockIdx.x * 256 + threadIdx.x;        // 65536 spatial
    int ow = p & 63, oh = (p >> 6) & 63, bb = p >> 12;   // ow == lane
    int oc0 = blockIdx.y * 16;
    float acc[16];
    #pragma unroll
    for (int j = 0; j < 16; ++j) acc[j] = 0.0f;
    const float* ibase = in + bb * 32 * 16384;

    float r0[4], r1[4];
    #pragma unroll
    for (int kh = 0; kh < 4; ++kh) {               // initial load, ic = 0
        int ih = oh * 2 - 1 + kh;                  // wave-uniform branch
        float v0 = 0.0f, v1 = 0.0f;
        if ((unsigned)ih < 128u) {
            float2 t = *(const float2*)(ibase + ih * 128 + 2 * ow);
            v0 = t.x; v1 = t.y;
        }
        r0[kh] = v0; r1[kh] = v1;
    }
    for (int ic = 0; ic < 32; ++ic) {
        float n0[4], n1[4];                         // prefetch ic+1 (clamped)
        int icn = (ic < 31) ? ic + 1 : 31;
        const float* ipn = ibase + icn * 16384;
        #pragma unroll
        for (int kh = 0; kh < 4; ++kh) {
            int ih = oh * 2 - 1 + kh;
            float v0 = 0.0f, v1 = 0.0f;
            if ((unsigned)ih < 128u) {
                float2 t = *(const float2*)(ipn + ih * 128 + 2 * ow);
                v0 = t.x; v1 = t.y;
            }
            n0[kh] = v0; n1[kh] = v1;
        }
        #pragma unroll
        for (int kh = 0; kh < 4; ++kh) {
            float t0 = __shfl_up(r1[kh], 1);
            if (ow == 0) t0 = 0.0f;                // iw = -1 pad
            float t3 = __shfl_down(r0[kh], 1);
            if (ow == 63) t3 = 0.0f;               // iw = 128 pad
            // packed: kw-group g at wkh[g*64 + j], j=0..15 contiguous
            const float* wkh = wp + (ic * 16 + kh * 4) * 64 + oc0;   // wave-uniform
            #pragma unroll
            for (int j = 0; j < 16; ++j) {
                acc[j] = __fmaf_rn(t0,     wkh[j],       acc[j]);
                acc[j] = __fmaf_rn(r0[kh], wkh[64 + j],  acc[j]);
                acc[j] = __fmaf_rn(r1[kh], wkh[128 + j], acc[j]);
                acc[j] = __fmaf_rn(t3,     wkh[192 + j], acc[j]);
            }
        }
        #pragma unroll
        for (int kh = 0; kh < 4; ++kh) { r0[kh] = n0[kh]; r1[kh] = n1[kh]; }
    }
    float* op = out + bb * (64 * 4096) + oh * 64 + ow;
    #pragma unroll
    for (int j = 0; j < 16; ++j) {
        float y = __fadd_rn(acc[j], bias[oc0 + j]);
        op[(oc0 + j) * 4096] = fmaxf(y, 0.0f);
    }
}

// ---------------- conv3: 1 row x 4 oc, half-wave rows, packed weights
__global__ __launch_bounds__(256) void conv3_kernel(const float* __restrict__ in,
                                                    const float* __restrict__ wp, // packed [ic*16+t][64]
                                                    const float* __restrict__ bias,
                                                    float* __restrict__ flat) {
    int p = blockIdx.x * 256 + threadIdx.x;        // 16384 (== flat row)
    int ow = p & 31, oh = (p >> 5) & 31, bb = p >> 10;   // ow == lane&31
    int oc0 = blockIdx.y * 4;
    float acc[4];
    #pragma unroll
    for (int j = 0; j < 4; ++j) acc[j] = 0.0f;
    const float* ibase = in + bb * 64 * 4096;

    float r0[4], r1[4];
    #pragma unroll
    for (int kh = 0; kh < 4; ++kh) {               // initial load, ic = 0
        int ih = oh * 2 - 1 + kh;
        float v0 = 0.0f, v1 = 0.0f;
        if ((unsigned)ih < 64u) {
            float2 t = *(const float2*)(ibase + ih * 64 + 2 * ow);
            v0 = t.x; v1 = t.y;
        }
        r0[kh] = v0; r1[kh] = v1;
    }
    for (int ic = 0; ic < 64; ++ic) {
        float n0[4], n1[4];                         // prefetch ic+1 (clamped)
        int icn = (ic < 63) ? ic + 1 : 63;
        const float* ipn = ibase + icn * 4096;
        #pragma unroll
        for (int kh = 0; kh < 4; ++kh) {
            int ih = oh * 2 - 1 + kh;
            float v0 = 0.0f, v1 = 0.0f;
            if ((unsigned)ih < 64u) {
                float2 t = *(const float2*)(ipn + ih * 64 + 2 * ow);
                v0 = t.x; v1 = t.y;
            }
            n0[kh] = v0; n1[kh] = v1;
        }
        #pragma unroll
        for (int kh = 0; kh < 4; ++kh) {
            float t0 = __shfl_up(r1[kh], 1);
            if (ow == 0) t0 = 0.0f;                // also kills cross-half garbage
            float t3 = __shfl_down(r0[kh], 1);
            if (ow == 31) t3 = 0.0f;               // also kills cross-half garbage
            const float* wkh = wp + (ic * 16 + kh * 4) * 64 + oc0;   // wave-uniform
            #pragma unroll
            for (int j = 0; j < 4; ++j) acc[j] = __fmaf_rn(t0,     wkh[j],       acc[j]);
            #pragma unroll
            for (int j = 0; j < 4; ++j) acc[j] = __fmaf_rn(r0[kh], wkh[64 + j],  acc[j]);
            #pragma unroll
            for (int j = 0; j < 4; ++j) acc[j] = __fmaf_rn(r1[kh], wkh[128 + j], acc[j]);
            #pragma unroll
            for (int j = 0; j < 4; ++j) acc[j] = __fmaf_rn(t3,     wkh[192 + j], acc[j]);
        }
        #pragma unroll
        for (int kh = 0; kh < 4; ++kh) { r0[kh] = n0[kh]; r1[kh] = n1[kh]; }
    }
    float* op = flat + (size_t)p * 64 + oc0;
    #pragma unroll
    for (int j = 0; j < 4; ++j) {
        float y = __fadd_rn(acc[j], bias[oc0 + j]);
        op[j] = fmaxf(y, 0.0f);
    }
}

// ---------------- row norms: sx[16384], sc[8192] (pairwise-8)
__global__ __launch_bounds__(256) void rownorm_kernel(const float* __restrict__ flat,
                                                      const float* __restrict__ cb,
                                                      float* __restrict__ sx,
                                                      float* __restrict__ sc) {
    int i = blockIdx.x * 256 + threadIdx.x;        // 24576
    const float* src;
    float* dst;
    if (i < 16384) { src = flat + (size_t)i * 64; dst = sx + i; }
    else           { src = cb + (size_t)(i - 16384) * 64; dst = sc + (i - 16384); }
    float r[8];
    #pragma unroll
    for (int j = 0; j < 8; ++j) r[j] = __fmul_rn(src[j], src[j]);
    #pragma unroll
    for (int b = 1; b < 8; ++b)
        #pragma unroll
        for (int j = 0; j < 8; ++j)
            r[j] = __fadd_rn(r[j], __fmul_rn(src[b * 8 + j], src[b * 8 + j]));
    float s01 = __fadd_rn(r[0], r[1]), s23 = __fadd_rn(r[2], r[3]);
    float s45 = __fadd_rn(r[4], r[5]), s67 = __fadd_rn(r[6], r[7]);
    *dst = __fadd_rn(__fadd_rn(s01, s23), __fadd_rn(s45, s67));
}

// ---------------- split: f32 -> bf16 hi/lo; zero count + tuple scalar
__global__ __launch_bounds__(256) void split_kernel(const float* __restrict__ flat,
                                                    const float* __restrict__ cb,
                                                    ushort_t* __restrict__ xh,
                                                    ushort_t* __restrict__ xl,
                                                    ushort_t* __restrict__ ch,
                                                    ushort_t* __restrict__ cl,
                                                    int* __restrict__ count,
                                                    float* __restrict__ out) {
    int i = blockIdx.x * 256 + threadIdx.x;        // 1572864
    if (i == 0) { *count = 0; out[16384] = 0.0f; }
    float v;
    ushort_t *ph, *pl;
    if (i < 1048576) { v = flat[i]; ph = xh + i; pl = xl + i; }
    else             { int j = i - 1048576; v = cb[j]; ph = ch + j; pl = cl + j; }
    unsigned short h = f2bf(v);
    unsigned short l = f2bf(v - bf2f(h));
    *ph = h; *pl = l;
}

// ---------------- MFMA screen: 256 row-blocks x 4 code-quarters; 2048 codes each.
// acc init = -sc/2 -> argmin(g) == argmax(acc). Ping-pong B buffers.
#define SCREEN_LOAD(BH0, BH1, BL0, BL1, SCV, COL)                         \
    {                                                                     \
        size_t br_ = (size_t)(COL) * 64 + lk * 8;                         \
        BH0 = *(const s16x8*)(ch + br_);                                  \
        BH1 = *(const s16x8*)(ch + br_ + 32);                             \
        BL0 = *(const s16x8*)(cl + br_);                                  \
        BL1 = *(const s16x8*)(cl + br_ + 32);                             \
        SCV = sc[COL];                                                    \
    }

#define SCREEN_COMPUTE(BH0, BH1, BL0, BL1, SCV, COL)                      \
    {                                                                     \
        float ini_ = __fmul_rn(-0.5f, SCV);                               \
        f32x4 acc[4];                                                     \
        _Pragma("unroll")                                                 \
        for (int i = 0; i < 4; ++i) acc[i] = (f32x4){ini_, ini_, ini_, ini_}; \
        _Pragma("unroll")                                                 \
        for (int i = 0; i < 4; ++i) acc[i] = __builtin_amdgcn_mfma_f32_16x16x32_bf16(a[i][0], BH0, acc[i], 0, 0, 0); \
        _Pragma("unroll")                                                 \
        for (int i = 0; i < 4; ++i) acc[i] = __builtin_amdgcn_mfma_f32_16x16x32_bf16(a[i][1], BH1, acc[i], 0, 0, 0); \
        _Pragma("unroll")                                                 \
        for (int i = 0; i < 4; ++i) acc[i] = __builtin_amdgcn_mfma_f32_16x16x32_bf16(a[i][0], BL0, acc[i], 0, 0, 0); \
        _Pragma("unroll")                                                 \
        for (int i = 0; i < 4; ++i) acc[i] = __builtin_amdgcn_mfma_f32_16x16x32_bf16(a[i][1], BL1, acc[i], 0, 0, 0); \
        _Pragma("unroll")                                                 \
        for (int i = 0; i < 4; ++i) acc[i] = __builtin_amdgcn_mfma_f32_16x16x32_bf16(a[i][2], BH0, acc[i], 0, 0, 0); \
        _Pragma("unroll")                                                 \
        for (int i = 0; i < 4; ++i) acc[i] = __builtin_amdgcn_mfma_f32_16x16x32_bf16(a[i][3], BH1, acc[i], 0, 0, 0); \
        _Pragma("unroll")                                                 \
        for (int i = 0; i < 4; ++i) {                                     \
            _Pragma("unroll")                                             \
            for (int reg = 0; reg < 4; ++reg) {                           \
                int s_ = i * 4 + reg;                                     \
                float av_ = acc[i][reg];                                  \
                m2[s_] = __builtin_amdgcn_fmed3f(m1[s_], m2[s_], av_);    \
                i1[s_] = (av_ > m1[s_]) ? (COL) : i1[s_];                 \
                m1[s_] = fmaxf(m1[s_], av_);                              \
            }                                                             \
        }                                                                 \
    }

__global__ __launch_bounds__(512, 2) void vq_screen_kernel(const ushort_t* __restrict__ xh,
                                                           const ushort_t* __restrict__ xl,
                                                           const ushort_t* __restrict__ ch,
                                                           const ushort_t* __restrict__ cl,
                                                           const float* __restrict__ sc,
                                                           float* __restrict__ pm1,   // [4][16384]
                                                           int* __restrict__ pi1,
                                                           float* __restrict__ pm2) {
    __shared__ float lm1[8][64];
    __shared__ int   li1[8][64];
    __shared__ float lm2[8][64];
    int tid = threadIdx.x;
    int row0 = blockIdx.x * 64;
    int quarter = blockIdx.y;
    int kbase = quarter * 2048;
    int w = tid >> 6, lane = tid & 63;
    int le = lane & 15, lk = lane >> 4;

    // A fragments in registers (reused across all codes) — kept resident
    s16x8 a[4][4];
    #pragma unroll
    for (int i = 0; i < 4; ++i) {
        size_t ar = (size_t)(row0 + i * 16 + le) * 64 + lk * 8;
        a[i][0] = *(const s16x8*)(xh + ar);
        a[i][1] = *(const s16x8*)(xh + ar + 32);
        a[i][2] = *(const s16x8*)(xl + ar);
        a[i][3] = *(const s16x8*)(xl + ar + 32);
    }

    float m1[16], m2[16];
    int i1[16];
    #pragma unroll
    for (int s = 0; s < 16; ++s) { m1[s] = -FLT_MAX; m2[s] = -FLT_MAX; i1[s] = 0x7fffffff; }

    int colbase = kbase + w * 16 + le;

    s16x8 b0h0, b0h1, b0l0, b0l1, b1h0, b1h1, b1l0, b1l1;
    float sc0, sc1;
    SCREEN_LOAD(b0h0, b0h1, b0l0, b0l1, sc0, colbase);      // nb = 0

    for (int nbp = 0; nbp < 8; ++nbp) {
        int colA = nbp * 256 + colbase;                      // nb = 2*nbp
        int colB = colA + 128;                               // nb = 2*nbp+1
        int colN = (nbp < 7) ? colA + 256 : colbase;         // wrap: redundant, unused
        SCREEN_LOAD(b1h0, b1h1, b1l0, b1l1, sc1, colB);
        SCREEN_COMPUTE(b0h0, b0h1, b0l0, b0l1, sc0, colA);
        SCREEN_LOAD(b0h0, b0h1, b0l0, b0l1, sc0, colN);
        SCREEN_COMPUTE(b1h0, b1h1, b1l0, b1l1, sc1, colB);
    }

    // merge across the 16 le-lanes (max domain)
    #pragma unroll
    for (int i = 0; i < 4; ++i) {
        #pragma unroll
        for (int reg = 0; reg < 4; ++reg) {
            int s = i * 4 + reg;
            float v1 = m1[s], v2 = m2[s];
            int ix = i1[s];
            #pragma unroll
            for (int mask = 1; mask < 16; mask <<= 1) {
                float o1 = __shfl_xor(v1, mask);
                int oi = __shfl_xor(ix, mask);
                float o2 = __shfl_xor(v2, mask);
                float n2 = fmaxf(fmaxf(v2, o2), fminf(v1, o1));
                ix = (o1 > v1) ? oi : ((o1 == v1 && oi < ix) ? oi : ix);
                v1 = fmaxf(v1, o1);
                v2 = n2;
            }
            if (le == 0) {
                int rl = i * 16 + lk * 4 + reg;
                lm1[w][rl] = v1; li1[w][rl] = ix; lm2[w][rl] = v2;
            }
        }
    }
    __syncthreads();
    if (tid < 64) {
        float M1 = -FLT_MAX, M2 = -FLT_MAX;
        int I1 = 0x7fffffff;
        #pragma unroll
        for (int ww = 0; ww < 8; ++ww) {
            float a1 = lm1[ww][tid], a2 = lm2[ww][tid];
            int ai = li1[ww][tid];
            M2 = fmaxf(fmaxf(M2, a2), fminf(M1, a1));
            if (a1 > M1 || (a1 == M1 && ai < I1)) I1 = ai;
            M1 = fmaxf(M1, a1);
        }
        size_t o = (size_t)quarter * 16384 + row0 + tid;   // row-major, coalesced
        pm1[o] = M1; pi1[o] = I1; pm2[o] = M2;
    }
}

// ---------------- merge: combine 4 quarters (max domain), gap test, out or flag
__global__ __launch_bounds__(256) void vq_merge_kernel(const float* __restrict__ pm1,
                                                       const int* __restrict__ pi1,
                                                       const float* __restrict__ pm2,
                                                       float* __restrict__ out,
                                                       int* __restrict__ count,
                                                       int* __restrict__ list,
                                                       u64* __restrict__ qbest) {
    int row = blockIdx.x * 256 + threadIdx.x;      // 16384
    float M1 = -FLT_MAX, M2 = -FLT_MAX;
    int I1 = 0x7fffffff;
    #pragma unroll
    for (int s = 0; s < 4; ++s) {                  // ascending s: lower code idx first
        float a1 = pm1[s * 16384 + row];
        float a2 = pm2[s * 16384 + row];
        int ai = pi1[s * 16384 + row];
        M2 = fmaxf(fmaxf(M2, a2), fminf(M1, a1));
        if (a1 > M1) { I1 = ai; M1 = a1; }         // tie keeps earlier (lower idx)
    }
    if (M1 - M2 >= TAU_ACC) {
        out[row] = (float)I1;                      // provably the replica argmin
    } else {
        qbest[row] = 0xFFFFFFFFFFFFFFFFull;
        int pos = atomicAdd(count, 1);
        list[pos] = row;
    }
}

// ---------------- fix: coalesced exact replica recompute of flagged rows.
// grid (16 rowchunk-strides, 64 codetiles); block = 64 rows x 128 codes.
#define FLDP 68
__global__ __launch_bounds__(256) void vq_fix_kernel(const float* __restrict__ flat,
                                                     const float* __restrict__ cb,
                                                     const float* __restrict__ sx,
                                                     const float* __restrict__ sc,
                                                     const int* __restrict__ count,
                                                     const int* __restrict__ list,
                                                     u64* __restrict__ qbest) {
    __shared__ float xs[64 * FLDP];
    __shared__ float cs[128 * FLDP];
    __shared__ float sxs[64], scs[128];
    __shared__ int rowids[64];
    int n = *count;
    int cb0 = blockIdx.y * 128;
    int tid = threadIdx.x;

    for (int rb = blockIdx.x; rb * 64 < n; rb += 16) {
        int nrows = n - rb * 64; if (nrows > 64) nrows = 64;

        // stage rows (gather) + sx + rowids
        #pragma unroll
        for (int s = 0; s < 4; ++s) {
            int idx = tid + 256 * s;               // 1024 float4s
            int r = idx >> 4, c = idx & 15;
            int rr = rb * 64 + r; if (rr >= n) rr = n - 1;
            int row = list[rr];
            if (c == 0) { rowids[r] = row; sxs[r] = sx[row]; }
            *(float4*)&xs[r * FLDP + c * 4] = *(const float4*)(flat + (size_t)row * 64 + c * 4);
        }
        // stage codes (coalesced)
        #pragma unroll
        for (int s = 0; s < 8; ++s) {
            int idx = tid + 256 * s;               // 2048 float4s
            int r = idx >> 4, c = idx & 15;
            *(float4*)&cs[r * FLDP + c * 4] = *(const float4*)(cb + (size_t)(cb0 + r) * 64 + c * 4);
        }
        if (tid < 128) scs[tid] = sc[cb0 + tid];
        __syncthreads();

        int tr = tid >> 4, tc = tid & 15;          // rows tr+16i (i<4), codes tc+16j (j<8)
        float acc[4][8];
        #pragma unroll
        for (int i = 0; i < 4; ++i)
            #pragma unroll
            for (int j = 0; j < 8; ++j) acc[i][j] = 0.0f;

        for (int d = 0; d < 64; d += 4) {          // strictly ascending d: replica chain
            float4 ax[4], bc[8];
            #pragma unroll
            for (int i = 0; i < 4; ++i) ax[i] = *(const float4*)&xs[(tr + 16 * i) * FLDP + d];
            #pragma unroll
            for (int j = 0; j < 8; ++j) bc[j] = *(const float4*)&cs[(tc + 16 * j) * FLDP + d];
            #pragma unroll
            for (int i = 0; i < 4; ++i)
                #pragma unroll
                for (int j = 0; j < 8; ++j) {
                    acc[i][j] = __fmaf_rn(ax[i].x, bc[j].x, acc[i][j]);
                    acc[i][j] = __fmaf_rn(ax[i].y, bc[j].y, acc[i][j]);
                    acc[i][j] = __fmaf_rn(ax[i].z, bc[j].z, acc[i][j]);
                    acc[i][j] = __fmaf_rn(ax[i].w, bc[j].w, acc[i][j]);
                }
        }

        float best[4];
        int bidx[4];
        #pragma unroll
        for (int i = 0; i < 4; ++i) { best[i] = FLT_MAX; bidx[i] = 0x7fffffff; }
        #pragma unroll
        for (int j = 0; j < 8; ++j) {              // ascending k within lane
            int k = cb0 + tc + 16 * j;
            float scj = scs[tc + 16 * j];
            #pragma unroll
            for (int i = 0; i < 4; ++i) {
                float t1 = __fadd_rn(sxs[tr + 16 * i], scj);
                float q = __fmaf_rn(-2.0f, acc[i][j], t1);   // replica q
                if (q < best[i]) { best[i] = q; bidx[i] = k; }
            }
        }

        // per-row merge across tc (reuse cs)
        __syncthreads();
        float* rmin = cs;                          // [64][16]
        int* ridx = (int*)(cs + 1024);             // [64][16]
        #pragma unroll
        for (int i = 0; i < 4; ++i) {
            rmin[(tr + 16 * i) * 16 + tc] = best[i];
            ridx[(tr + 16 * i) * 16 + tc] = bidx[i];
        }
        __syncthreads();
        if (tid < nrows) {
            float m = FLT_MAX; int mi = 0x7fffffff;
            for (int t2 = 0; t2 < 16; ++t2) {
                float v = rmin[tid * 16 + t2];
                int ix = ridx[tid * 16 + t2];
                if (v < m || (v == m && ix < mi)) { m = v; mi = ix; }
            }
            u64 key = ((u64)__float_as_uint(m) << 32) | (unsigned)mi;  // q>0 -> order ok
            atomicMin(&qbest[rowids[tid]], key);
        }
        __syncthreads();                           // cs/xs reuse safe for next rb
    }
}

// ---------------- vq_out: write flagged rows from qbest
__global__ __launch_bounds__(256) void vq_out_kernel(const int* __restrict__ count,
                                                     const int* __restrict__ list,
                                                     const u64* __restrict__ qbest,
                                                     float* __restrict__ out) {
    int pos = blockIdx.x * 256 + threadIdx.x;      // 16384
    if (pos >= *count) return;
    int row = list[pos];
    out[row] = (float)(unsigned)(qbest[row] & 0xffffffffull);
}

extern "C" void kernel_launch(void* const* d_in, const int* in_sizes, int n_in,
                              void* d_out, int out_size, void* d_ws, size_t ws_size,
                              hipStream_t stream) {
    const float* x  = (const float*)d_in[0];
    const float* w1 = (const float*)d_in[1];
    const float* b1 = (const float*)d_in[2];
    const float* w2 = (const float*)d_in[3];
    const float* b2 = (const float*)d_in[4];
    const float* w3 = (const float*)d_in[5];
    const float* b3 = (const float*)d_in[6];
    const float* cb = (const float*)d_in[7];

    float* ws   = (float*)d_ws;
    float* out1 = ws;                               // [0, 8388608)
    ushort_t* xh = (ushort_t*)(ws + 0);             // aliases out1 (post-conv2)
    ushort_t* xl = (ushort_t*)(ws + 524288);
    ushort_t* ch = (ushort_t*)(ws + 1048576);
    ushort_t* cl = (ushort_t*)(ws + 1310720);       // slots [1310720, 1572864)
    float* pm1  = ws + 1572864;                     // [4][16384]
    int*   pi1  = (int*)(ws + 1638400);             // [4][16384]
    float* pm2  = ws + 1703936;                     // [4][16384], ends 1769472
    float* out2 = ws + 8388608;
    float* flat = ws + 12582912;
    float* sx   = ws + 13631488;
    float* sc   = ws + 13647872;
    int*   count = (int*)(ws + 13656064);
    int*   list  = (int*)(ws + 13656320);
    u64*   qbest = (u64*)(ws + 13672704);           // 32768 slots, ends 13705472
    float* wp2  = ws + 13705472;                    // [32768]
    float* wp3  = ws + 13738240;                    // [65536], ends 13803776
    float* out  = (float*)d_out;

    hipLaunchKernelGGL(wpack_kernel,  dim3(384), dim3(256), 0, stream, w2, w3, wp2, wp3);
    hipLaunchKernelGGL(conv1_kernel,  dim3(1024, 2), dim3(256), 0, stream, x, w1, b1, out1);
    hipLaunchKernelGGL(conv2_kernel,  dim3(256, 4), dim3(256), 0, stream, out1, wp2, b2, out2);
    hipLaunchKernelGGL(conv3_kernel,  dim3(64, 16), dim3(256), 0, stream, out2, wp3, b3, flat);
    hipLaunchKernelGGL(rownorm_kernel, dim3(96), dim3(256), 0, stream, flat, cb, sx, sc);
    hipLaunchKernelGGL(split_kernel,  dim3(6144), dim3(256), 0, stream, flat, cb, xh, xl, ch, cl, count, out);
    hipLaunchKernelGGL(vq_screen_kernel, dim3(256, 4), dim3(512), 0, stream,
                       xh, xl, ch, cl, sc, pm1, pi1, pm2);
    hipLaunchKernelGGL(vq_merge_kernel, dim3(64), dim3(256), 0, stream,
                       pm1, pi1, pm2, out, count, list, qbest);
    hipLaunchKernelGGL(vq_fix_kernel, dim3(16, 64), dim3(256), 0, stream,
                       flat, cb, sx, sc, count, list, qbest);
    hipLaunchKernelGGL(vq_out_kernel, dim3(64), dim3(256), 0, stream, count, list, qbest, out);
}

// Round 21
// 270.065 us; speedup vs baseline: 1.1060x; 1.1060x over previous
//
#include <hip/hip_runtime.h>
#include <float.h>

// r19 config (best measured: 279 us) + r21 single change: conv3 8 oc/thread.
// r20's screen 4-way split reverted (regressed 89->109 us; Occ pinned ~21%
// regardless of grid -> fewer, longer blocks win).
// Replica-f32 semantics (bit-exact vs np reference) unchanged throughout.
//
// Workspace (float slots). ushort arrays occupy size/2 slots.
//   out1 : ws[0 .. 8388608)
//     xh  = ws+0        ushort[1048576]  -> slots [0,       524288)
//     xl  = ws+524288   ushort[1048576]  -> slots [524288, 1048576)
//     ch  = ws+1048576  ushort[524288]   -> slots [1048576,1310720)
//     cl  = ws+1310720  ushort[524288]   -> slots [1310720,1572864)
//     pm1 = ws+1572864  [2][16384] f32
//     pi1 = ws+1605632  [2][16384] i32
//     pm2 = ws+1638400  [2][16384] f32   (ends 1671168 < 8388608)
//   out2 : ws+8388608   [16][64][64][64]
//   flat : ws+12582912  [16384][64]
//   sx   : ws+13631488  [16384]
//   sc   : ws+13647872  [8192]
//   count: ws+13656064  (int)
//   list : ws+13656320  (int[16384])
//   qbest: ws+13672704  (u64[16384] = 32768 slots, ends 13705472)
//   wp2  : ws+13705472  [32768]  packed conv2 weights
//   wp3  : ws+13738240  [65536]  packed conv3 weights (ends 13803776)

#define TAU_ACC 2e-6f   // acc-domain gap threshold (= TAU/2, TAU=4e-6 in g)

typedef __attribute__((ext_vector_type(8))) short s16x8;
typedef __attribute__((ext_vector_type(4))) float f32x4;
typedef unsigned short ushort_t;
typedef unsigned long long u64;

static __device__ __forceinline__ unsigned short f2bf(float f) {
    unsigned u = __float_as_uint(f);
    u = (u + 0x7fffu + ((u >> 16) & 1u)) >> 16;    // RN-even; no NaN in this data
    return (unsigned short)u;
}
static __device__ __forceinline__ float bf2f(unsigned short h) {
    return __uint_as_float(((unsigned)h) << 16);
}

// ---------------- weight repack: w[oc][ic][kh][kw] -> wpack[(ic*16+t)*OC + oc]
__global__ __launch_bounds__(256) void wpack_kernel(const float* __restrict__ w2,
                                                    const float* __restrict__ w3,
                                                    float* __restrict__ wp2,
                                                    float* __restrict__ wp3) {
    int i = blockIdx.x * 256 + threadIdx.x;        // 98304
    if (i < 32768) {                               // w2: [64][32][4][4]
        int oc = i >> 9, rem = i & 511;
        int ic = rem >> 4, t = rem & 15;
        wp2[(ic * 16 + t) * 64 + oc] = w2[i];
    } else if (i < 98304) {                        // w3: [64][64][4][4]
        int j = i - 32768;
        int oc = j >> 10, rem = j & 1023;
        int ic = rem >> 4, t = rem & 15;
        wp3[(ic * 16 + t) * 64 + oc] = w3[j];
    }
}

// ---------------- conv1: x[16,3,256,256] -> relu -> out1[16,32,128,128], k4 s2 p1
__global__ __launch_bounds__(256) void conv1_kernel(const float* __restrict__ in,
                                                    const float* __restrict__ w,   // [32][3][4][4]
                                                    const float* __restrict__ bias,// [32]
                                                    float* __restrict__ out) {
    int p = blockIdx.x * 256 + threadIdx.x;        // 262144
    int ow = p & 127, oh = (p >> 7) & 127, bb = p >> 14;
    int oc0 = blockIdx.y * 16;
    float taps[48];                                 // [ic][kh][kw]
    for (int ic = 0; ic < 3; ++ic) {
        const float* ip = in + (bb * 3 + ic) * 65536;
        #pragma unroll
        for (int kh = 0; kh < 4; ++kh) {
            int ih = oh * 2 - 1 + kh;
            #pragma unroll
            for (int kw = 0; kw < 4; ++kw) {
                int iw = ow * 2 - 1 + kw;
                bool ok = ((unsigned)ih < 256u) && ((unsigned)iw < 256u);
                taps[ic * 16 + kh * 4 + kw] = ok ? ip[ih * 256 + iw] : 0.0f;
            }
        }
    }
    float* op = out + bb * (32 * 16384) + oh * 128 + ow;
    for (int oc = oc0; oc < oc0 + 16; ++oc) {
        float acc = 0.0f;
        const float* wp = w + oc * 48;             // wave-uniform
        #pragma unroll
        for (int t = 0; t < 48; ++t) acc = __fmaf_rn(taps[t], wp[t], acc);
        acc = __fadd_rn(acc, bias[oc]);
        op[oc * 16384] = fmaxf(acc, 0.0f);
    }
}

// ---------------- conv2: 1 row x 16 oc, packed weights (contiguous s_loads)
__global__ __launch_bounds__(256, 4) void conv2_kernel(const float* __restrict__ in,
                                                       const float* __restrict__ wp, // packed [ic*16+t][64]
                                                       const float* __restrict__ bias,
                                                       float* __restrict__ out) {
    int p = blockIdx.x * 256 + threadIdx.x;        // 65536 spatial
    int ow = p & 63, oh = (p >> 6) & 63, bb = p >> 12;   // ow == lane
    int oc0 = blockIdx.y * 16;
    float acc[16];
    #pragma unroll
    for (int j = 0; j < 16; ++j) acc[j] = 0.0f;
    const float* ibase = in + bb * 32 * 16384;

    float r0[4], r1[4];
    #pragma unroll
    for (int kh = 0; kh < 4; ++kh) {               // initial load, ic = 0
        int ih = oh * 2 - 1 + kh;                  // wave-uniform branch
        float v0 = 0.0f, v1 = 0.0f;
        if ((unsigned)ih < 128u) {
            float2 t = *(const float2*)(ibase + ih * 128 + 2 * ow);
            v0 = t.x; v1 = t.y;
        }
        r0[kh] = v0; r1[kh] = v1;
    }
    for (int ic = 0; ic < 32; ++ic) {
        float n0[4], n1[4];                         // prefetch ic+1 (clamped)
        int icn = (ic < 31) ? ic + 1 : 31;
        const float* ipn = ibase + icn * 16384;
        #pragma unroll
        for (int kh = 0; kh < 4; ++kh) {
            int ih = oh * 2 - 1 + kh;
            float v0 = 0.0f, v1 = 0.0f;
            if ((unsigned)ih < 128u) {
                float2 t = *(const float2*)(ipn + ih * 128 + 2 * ow);
                v0 = t.x; v1 = t.y;
            }
            n0[kh] = v0; n1[kh] = v1;
        }
        #pragma unroll
        for (int kh = 0; kh < 4; ++kh) {
            float t0 = __shfl_up(r1[kh], 1);
            if (ow == 0) t0 = 0.0f;                // iw = -1 pad
            float t3 = __shfl_down(r0[kh], 1);
            if (ow == 63) t3 = 0.0f;               // iw = 128 pad
            // packed: kw-group g at wkh[g*64 + j], j=0..15 contiguous
            const float* wkh = wp + (ic * 16 + kh * 4) * 64 + oc0;   // wave-uniform
            #pragma unroll
            for (int j = 0; j < 16; ++j) {
                acc[j] = __fmaf_rn(t0,     wkh[j],       acc[j]);
                acc[j] = __fmaf_rn(r0[kh], wkh[64 + j],  acc[j]);
                acc[j] = __fmaf_rn(r1[kh], wkh[128 + j], acc[j]);
                acc[j] = __fmaf_rn(t3,     wkh[192 + j], acc[j]);
            }
        }
        #pragma unroll
        for (int kh = 0; kh < 4; ++kh) { r0[kh] = n0[kh]; r1[kh] = n1[kh]; }
    }
    float* op = out + bb * (64 * 4096) + oh * 64 + ow;
    #pragma unroll
    for (int j = 0; j < 16; ++j) {
        float y = __fadd_rn(acc[j], bias[oc0 + j]);
        op[(oc0 + j) * 4096] = fmaxf(y, 0.0f);
    }
}

// ---------------- conv3: 1 row x 8 oc, half-wave rows, packed weights
__global__ __launch_bounds__(256) void conv3_kernel(const float* __restrict__ in,
                                                    const float* __restrict__ wp, // packed [ic*16+t][64]
                                                    const float* __restrict__ bias,
                                                    float* __restrict__ flat) {
    int p = blockIdx.x * 256 + threadIdx.x;        // 16384 (== flat row)
    int ow = p & 31, oh = (p >> 5) & 31, bb = p >> 10;   // ow == lane&31
    int oc0 = blockIdx.y * 8;
    float acc[8];
    #pragma unroll
    for (int j = 0; j < 8; ++j) acc[j] = 0.0f;
    const float* ibase = in + bb * 64 * 4096;

    float r0[4], r1[4];
    #pragma unroll
    for (int kh = 0; kh < 4; ++kh) {               // initial load, ic = 0
        int ih = oh * 2 - 1 + kh;
        float v0 = 0.0f, v1 = 0.0f;
        if ((unsigned)ih < 64u) {
            float2 t = *(const float2*)(ibase + ih * 64 + 2 * ow);
            v0 = t.x; v1 = t.y;
        }
        r0[kh] = v0; r1[kh] = v1;
    }
    for (int ic = 0; ic < 64; ++ic) {
        float n0[4], n1[4];                         // prefetch ic+1 (clamped)
        int icn = (ic < 63) ? ic + 1 : 63;
        const float* ipn = ibase + icn * 4096;
        #pragma unroll
        for (int kh = 0; kh < 4; ++kh) {
            int ih = oh * 2 - 1 + kh;
            float v0 = 0.0f, v1 = 0.0f;
            if ((unsigned)ih < 64u) {
                float2 t = *(const float2*)(ipn + ih * 64 + 2 * ow);
                v0 = t.x; v1 = t.y;
            }
            n0[kh] = v0; n1[kh] = v1;
        }
        #pragma unroll
        for (int kh = 0; kh < 4; ++kh) {
            float t0 = __shfl_up(r1[kh], 1);
            if (ow == 0) t0 = 0.0f;                // also kills cross-half garbage
            float t3 = __shfl_down(r0[kh], 1);
            if (ow == 31) t3 = 0.0f;               // also kills cross-half garbage
            const float* wkh = wp + (ic * 16 + kh * 4) * 64 + oc0;   // wave-uniform
            #pragma unroll
            for (int j = 0; j < 8; ++j) {
                acc[j] = __fmaf_rn(t0,     wkh[j],       acc[j]);
                acc[j] = __fmaf_rn(r0[kh], wkh[64 + j],  acc[j]);
                acc[j] = __fmaf_rn(r1[kh], wkh[128 + j], acc[j]);
                acc[j] = __fmaf_rn(t3,     wkh[192 + j], acc[j]);
            }
        }
        #pragma unroll
        for (int kh = 0; kh < 4; ++kh) { r0[kh] = n0[kh]; r1[kh] = n1[kh]; }
    }
    float* op = flat + (size_t)p * 64 + oc0;
    #pragma unroll
    for (int j = 0; j < 8; ++j) {
        float y = __fadd_rn(acc[j], bias[oc0 + j]);
        op[j] = fmaxf(y, 0.0f);
    }
}

// ---------------- row norms: sx[16384], sc[8192] (pairwise-8)
__global__ __launch_bounds__(256) void rownorm_kernel(const float* __restrict__ flat,
                                                      const float* __restrict__ cb,
                                                      float* __restrict__ sx,
                                                      float* __restrict__ sc) {
    int i = blockIdx.x * 256 + threadIdx.x;        // 24576
    const float* src;
    float* dst;
    if (i < 16384) { src = flat + (size_t)i * 64; dst = sx + i; }
    else           { src = cb + (size_t)(i - 16384) * 64; dst = sc + (i - 16384); }
    float r[8];
    #pragma unroll
    for (int j = 0; j < 8; ++j) r[j] = __fmul_rn(src[j], src[j]);
    #pragma unroll
    for (int b = 1; b < 8; ++b)
        #pragma unroll
        for (int j = 0; j < 8; ++j)
            r[j] = __fadd_rn(r[j], __fmul_rn(src[b * 8 + j], src[b * 8 + j]));
    float s01 = __fadd_rn(r[0], r[1]), s23 = __fadd_rn(r[2], r[3]);
    float s45 = __fadd_rn(r[4], r[5]), s67 = __fadd_rn(r[6], r[7]);
    *dst = __fadd_rn(__fadd_rn(s01, s23), __fadd_rn(s45, s67));
}

// ---------------- split: f32 -> bf16 hi/lo; zero count + tuple scalar
__global__ __launch_bounds__(256) void split_kernel(const float* __restrict__ flat,
                                                    const float* __restrict__ cb,
                                                    ushort_t* __restrict__ xh,
                                                    ushort_t* __restrict__ xl,
                                                    ushort_t* __restrict__ ch,
                                                    ushort_t* __restrict__ cl,
                                                    int* __restrict__ count,
                                                    float* __restrict__ out) {
    int i = blockIdx.x * 256 + threadIdx.x;        // 1572864
    if (i == 0) { *count = 0; out[16384] = 0.0f; }
    float v;
    ushort_t *ph, *pl;
    if (i < 1048576) { v = flat[i]; ph = xh + i; pl = xl + i; }
    else             { int j = i - 1048576; v = cb[j]; ph = ch + j; pl = cl + j; }
    unsigned short h = f2bf(v);
    unsigned short l = f2bf(v - bf2f(h));
    *ph = h; *pl = l;
}

// ---------------- MFMA screen: 256 row-blocks x 2 code-halves; 4096 codes each.
// acc init = -sc/2 -> argmin(g) == argmax(acc). Ping-pong B buffers.
#define SCREEN_LOAD(BH0, BH1, BL0, BL1, SCV, COL)                         \
    {                                                                     \
        size_t br_ = (size_t)(COL) * 64 + lk * 8;                         \
        BH0 = *(const s16x8*)(ch + br_);                                  \
        BH1 = *(const s16x8*)(ch + br_ + 32);                             \
        BL0 = *(const s16x8*)(cl + br_);                                  \
        BL1 = *(const s16x8*)(cl + br_ + 32);                             \
        SCV = sc[COL];                                                    \
    }

#define SCREEN_COMPUTE(BH0, BH1, BL0, BL1, SCV, COL)                      \
    {                                                                     \
        float ini_ = __fmul_rn(-0.5f, SCV);                               \
        f32x4 acc[4];                                                     \
        _Pragma("unroll")                                                 \
        for (int i = 0; i < 4; ++i) acc[i] = (f32x4){ini_, ini_, ini_, ini_}; \
        _Pragma("unroll")                                                 \
        for (int i = 0; i < 4; ++i) acc[i] = __builtin_amdgcn_mfma_f32_16x16x32_bf16(a[i][0], BH0, acc[i], 0, 0, 0); \
        _Pragma("unroll")                                                 \
        for (int i = 0; i < 4; ++i) acc[i] = __builtin_amdgcn_mfma_f32_16x16x32_bf16(a[i][1], BH1, acc[i], 0, 0, 0); \
        _Pragma("unroll")                                                 \
        for (int i = 0; i < 4; ++i) acc[i] = __builtin_amdgcn_mfma_f32_16x16x32_bf16(a[i][0], BL0, acc[i], 0, 0, 0); \
        _Pragma("unroll")                                                 \
        for (int i = 0; i < 4; ++i) acc[i] = __builtin_amdgcn_mfma_f32_16x16x32_bf16(a[i][1], BL1, acc[i], 0, 0, 0); \
        _Pragma("unroll")                                                 \
        for (int i = 0; i < 4; ++i) acc[i] = __builtin_amdgcn_mfma_f32_16x16x32_bf16(a[i][2], BH0, acc[i], 0, 0, 0); \
        _Pragma("unroll")                                                 \
        for (int i = 0; i < 4; ++i) acc[i] = __builtin_amdgcn_mfma_f32_16x16x32_bf16(a[i][3], BH1, acc[i], 0, 0, 0); \
        _Pragma("unroll")                                                 \
        for (int i = 0; i < 4; ++i) {                                     \
            _Pragma("unroll")                                             \
            for (int reg = 0; reg < 4; ++reg) {                           \
                int s_ = i * 4 + reg;                                     \
                float av_ = acc[i][reg];                                  \
                m2[s_] = __builtin_amdgcn_fmed3f(m1[s_], m2[s_], av_);    \
                i1[s_] = (av_ > m1[s_]) ? (COL) : i1[s_];                 \
                m1[s_] = fmaxf(m1[s_], av_);                              \
            }                                                             \
        }                                                                 \
    }

__global__ __launch_bounds__(512, 2) void vq_screen_kernel(const ushort_t* __restrict__ xh,
                                                           const ushort_t* __restrict__ xl,
                                                           const ushort_t* __restrict__ ch,
                                                           const ushort_t* __restrict__ cl,
                                                           const float* __restrict__ sc,
                                                           float* __restrict__ pm1,   // [2][16384]
                                                           int* __restrict__ pi1,
                                                           float* __restrict__ pm2) {
    __shared__ float lm1[8][64];
    __shared__ int   li1[8][64];
    __shared__ float lm2[8][64];
    int tid = threadIdx.x;
    int row0 = blockIdx.x * 64;
    int half = blockIdx.y;
    int kbase = half * 4096;
    int w = tid >> 6, lane = tid & 63;
    int le = lane & 15, lk = lane >> 4;

    // A fragments in registers (reused across all codes) — kept resident
    s16x8 a[4][4];
    #pragma unroll
    for (int i = 0; i < 4; ++i) {
        size_t ar = (size_t)(row0 + i * 16 + le) * 64 + lk * 8;
        a[i][0] = *(const s16x8*)(xh + ar);
        a[i][1] = *(const s16x8*)(xh + ar + 32);
        a[i][2] = *(const s16x8*)(xl + ar);
        a[i][3] = *(const s16x8*)(xl + ar + 32);
    }

    float m1[16], m2[16];
    int i1[16];
    #pragma unroll
    for (int s = 0; s < 16; ++s) { m1[s] = -FLT_MAX; m2[s] = -FLT_MAX; i1[s] = 0x7fffffff; }

    int colbase = kbase + w * 16 + le;

    s16x8 b0h0, b0h1, b0l0, b0l1, b1h0, b1h1, b1l0, b1l1;
    float sc0, sc1;
    SCREEN_LOAD(b0h0, b0h1, b0l0, b0l1, sc0, colbase);      // nb = 0

    for (int nbp = 0; nbp < 16; ++nbp) {
        int colA = nbp * 256 + colbase;                      // nb = 2*nbp
        int colB = colA + 128;                               // nb = 2*nbp+1
        int colN = (nbp < 15) ? colA + 256 : colbase;        // wrap: redundant, unused
        SCREEN_LOAD(b1h0, b1h1, b1l0, b1l1, sc1, colB);
        SCREEN_COMPUTE(b0h0, b0h1, b0l0, b0l1, sc0, colA);
        SCREEN_LOAD(b0h0, b0h1, b0l0, b0l1, sc0, colN);
        SCREEN_COMPUTE(b1h0, b1h1, b1l0, b1l1, sc1, colB);
    }

    // merge across the 16 le-lanes (max domain)
    #pragma unroll
    for (int i = 0; i < 4; ++i) {
        #pragma unroll
        for (int reg = 0; reg < 4; ++reg) {
            int s = i * 4 + reg;
            float v1 = m1[s], v2 = m2[s];
            int ix = i1[s];
            #pragma unroll
            for (int mask = 1; mask < 16; mask <<= 1) {
                float o1 = __shfl_xor(v1, mask);
                int oi = __shfl_xor(ix, mask);
                float o2 = __shfl_xor(v2, mask);
                float n2 = fmaxf(fmaxf(v2, o2), fminf(v1, o1));
                ix = (o1 > v1) ? oi : ((o1 == v1 && oi < ix) ? oi : ix);
                v1 = fmaxf(v1, o1);
                v2 = n2;
            }
            if (le == 0) {
                int rl = i * 16 + lk * 4 + reg;
                lm1[w][rl] = v1; li1[w][rl] = ix; lm2[w][rl] = v2;
            }
        }
    }
    __syncthreads();
    if (tid < 64) {
        float M1 = -FLT_MAX, M2 = -FLT_MAX;
        int I1 = 0x7fffffff;
        #pragma unroll
        for (int ww = 0; ww < 8; ++ww) {
            float a1 = lm1[ww][tid], a2 = lm2[ww][tid];
            int ai = li1[ww][tid];
            M2 = fmaxf(fmaxf(M2, a2), fminf(M1, a1));
            if (a1 > M1 || (a1 == M1 && ai < I1)) I1 = ai;
            M1 = fmaxf(M1, a1);
        }
        size_t o = (size_t)half * 16384 + row0 + tid;   // row-major, coalesced
        pm1[o] = M1; pi1[o] = I1; pm2[o] = M2;
    }
}

// ---------------- merge: combine 2 halves (max domain), gap test, out or flag
__global__ __launch_bounds__(256) void vq_merge_kernel(const float* __restrict__ pm1,
                                                       const int* __restrict__ pi1,
                                                       const float* __restrict__ pm2,
                                                       float* __restrict__ out,
                                                       int* __restrict__ count,
                                                       int* __restrict__ list,
                                                       u64* __restrict__ qbest) {
    int row = blockIdx.x * 256 + threadIdx.x;      // 16384
    float a1 = pm1[row], b1 = pm1[16384 + row];
    int ai = pi1[row], bi = pi1[16384 + row];
    float a2 = pm2[row], b2 = pm2[16384 + row];
    float M1 = fmaxf(a1, b1);
    int I1 = (b1 > a1) ? bi : ai;                  // tie -> ai (half-0 has lower idx)
    float M2 = fmaxf(fmaxf(a2, b2), fminf(a1, b1));
    if (M1 - M2 >= TAU_ACC) {
        out[row] = (float)I1;                      // provably the replica argmin
    } else {
        qbest[row] = 0xFFFFFFFFFFFFFFFFull;
        int pos = atomicAdd(count, 1);
        list[pos] = row;
    }
}

// ---------------- fix: coalesced exact replica recompute of flagged rows.
// grid (16 rowchunk-strides, 64 codetiles); block = 64 rows x 128 codes.
#define FLDP 68
__global__ __launch_bounds__(256) void vq_fix_kernel(const float* __restrict__ flat,
                                                     const float* __restrict__ cb,
                                                     const float* __restrict__ sx,
                                                     const float* __restrict__ sc,
                                                     const int* __restrict__ count,
                                                     const int* __restrict__ list,
                                                     u64* __restrict__ qbest) {
    __shared__ float xs[64 * FLDP];
    __shared__ float cs[128 * FLDP];
    __shared__ float sxs[64], scs[128];
    __shared__ int rowids[64];
    int n = *count;
    int cb0 = blockIdx.y * 128;
    int tid = threadIdx.x;

    for (int rb = blockIdx.x; rb * 64 < n; rb += 16) {
        int nrows = n - rb * 64; if (nrows > 64) nrows = 64;

        // stage rows (gather) + sx + rowids
        #pragma unroll
        for (int s = 0; s < 4; ++s) {
            int idx = tid + 256 * s;               // 1024 float4s
            int r = idx >> 4, c = idx & 15;
            int rr = rb * 64 + r; if (rr >= n) rr = n - 1;
            int row = list[rr];
            if (c == 0) { rowids[r] = row; sxs[r] = sx[row]; }
            *(float4*)&xs[r * FLDP + c * 4] = *(const float4*)(flat + (size_t)row * 64 + c * 4);
        }
        // stage codes (coalesced)
        #pragma unroll
        for (int s = 0; s < 8; ++s) {
            int idx = tid + 256 * s;               // 2048 float4s
            int r = idx >> 4, c = idx & 15;
            *(float4*)&cs[r * FLDP + c * 4] = *(const float4*)(cb + (size_t)(cb0 + r) * 64 + c * 4);
        }
        if (tid < 128) scs[tid] = sc[cb0 + tid];
        __syncthreads();

        int tr = tid >> 4, tc = tid & 15;          // rows tr+16i (i<4), codes tc+16j (j<8)
        float acc[4][8];
        #pragma unroll
        for (int i = 0; i < 4; ++i)
            #pragma unroll
            for (int j = 0; j < 8; ++j) acc[i][j] = 0.0f;

        for (int d = 0; d < 64; d += 4) {          // strictly ascending d: replica chain
            float4 ax[4], bc[8];
            #pragma unroll
            for (int i = 0; i < 4; ++i) ax[i] = *(const float4*)&xs[(tr + 16 * i) * FLDP + d];
            #pragma unroll
            for (int j = 0; j < 8; ++j) bc[j] = *(const float4*)&cs[(tc + 16 * j) * FLDP + d];
            #pragma unroll
            for (int i = 0; i < 4; ++i)
                #pragma unroll
                for (int j = 0; j < 8; ++j) {
                    acc[i][j] = __fmaf_rn(ax[i].x, bc[j].x, acc[i][j]);
                    acc[i][j] = __fmaf_rn(ax[i].y, bc[j].y, acc[i][j]);
                    acc[i][j] = __fmaf_rn(ax[i].z, bc[j].z, acc[i][j]);
                    acc[i][j] = __fmaf_rn(ax[i].w, bc[j].w, acc[i][j]);
                }
        }

        float best[4];
        int bidx[4];
        #pragma unroll
        for (int i = 0; i < 4; ++i) { best[i] = FLT_MAX; bidx[i] = 0x7fffffff; }
        #pragma unroll
        for (int j = 0; j < 8; ++j) {              // ascending k within lane
            int k = cb0 + tc + 16 * j;
            float scj = scs[tc + 16 * j];
            #pragma unroll
            for (int i = 0; i < 4; ++i) {
                float t1 = __fadd_rn(sxs[tr + 16 * i], scj);
                float q = __fmaf_rn(-2.0f, acc[i][j], t1);   // replica q
                if (q < best[i]) { best[i] = q; bidx[i] = k; }
            }
        }

        // per-row merge across tc (reuse cs)
        __syncthreads();
        float* rmin = cs;                          // [64][16]
        int* ridx = (int*)(cs + 1024);             // [64][16]
        #pragma unroll
        for (int i = 0; i < 4; ++i) {
            rmin[(tr + 16 * i) * 16 + tc] = best[i];
            ridx[(tr + 16 * i) * 16 + tc] = bidx[i];
        }
        __syncthreads();
        if (tid < nrows) {
            float m = FLT_MAX; int mi = 0x7fffffff;
            for (int t2 = 0; t2 < 16; ++t2) {
                float v = rmin[tid * 16 + t2];
                int ix = ridx[tid * 16 + t2];
                if (v < m || (v == m && ix < mi)) { m = v; mi = ix; }
            }
            u64 key = ((u64)__float_as_uint(m) << 32) | (unsigned)mi;  // q>0 -> order ok
            atomicMin(&qbest[rowids[tid]], key);
        }
        __syncthreads();                           // cs/xs reuse safe for next rb
    }
}

// ---------------- vq_out: write flagged rows from qbest
__global__ __launch_bounds__(256) void vq_out_kernel(const int* __restrict__ count,
                                                     const int* __restrict__ list,
                                                     const u64* __restrict__ qbest,
                                                     float* __restrict__ out) {
    int pos = blockIdx.x * 256 + threadIdx.x;      // 16384
    if (pos >= *count) return;
    int row = list[pos];
    out[row] = (float)(unsigned)(qbest[row] & 0xffffffffull);
}

extern "C" void kernel_launch(void* const* d_in, const int* in_sizes, int n_in,
                              void* d_out, int out_size, void* d_ws, size_t ws_size,
                              hipStream_t stream) {
    const float* x  = (const float*)d_in[0];
    const float* w1 = (const float*)d_in[1];
    const float* b1 = (const float*)d_in[2];
    const float* w2 = (const float*)d_in[3];
    const float* b2 = (const float*)d_in[4];
    const float* w3 = (const float*)d_in[5];
    const float* b3 = (const float*)d_in[6];
    const float* cb = (const float*)d_in[7];

    float* ws   = (float*)d_ws;
    float* out1 = ws;                               // [0, 8388608)
    ushort_t* xh = (ushort_t*)(ws + 0);             // aliases out1 (post-conv2)
    ushort_t* xl = (ushort_t*)(ws + 524288);
    ushort_t* ch = (ushort_t*)(ws + 1048576);
    ushort_t* cl = (ushort_t*)(ws + 1310720);       // slots [1310720, 1572864)
    float* pm1  = ws + 1572864;                     // [2][16384]
    int*   pi1  = (int*)(ws + 1605632);
    float* pm2  = ws + 1638400;                     // ends 1671168 < 8388608
    float* out2 = ws + 8388608;
    float* flat = ws + 12582912;
    float* sx   = ws + 13631488;
    float* sc   = ws + 13647872;
    int*   count = (int*)(ws + 13656064);
    int*   list  = (int*)(ws + 13656320);
    u64*   qbest = (u64*)(ws + 13672704);           // 32768 slots, ends 13705472
    float* wp2  = ws + 13705472;                    // [32768]
    float* wp3  = ws + 13738240;                    // [65536], ends 13803776
    float* out  = (float*)d_out;

    hipLaunchKernelGGL(wpack_kernel,  dim3(384), dim3(256), 0, stream, w2, w3, wp2, wp3);
    hipLaunchKernelGGL(conv1_kernel,  dim3(1024, 2), dim3(256), 0, stream, x, w1, b1, out1);
    hipLaunchKernelGGL(conv2_kernel,  dim3(256, 4), dim3(256), 0, stream, out1, wp2, b2, out2);
    hipLaunchKernelGGL(conv3_kernel,  dim3(64, 8), dim3(256), 0, stream, out2, wp3, b3, flat);
    hipLaunchKernelGGL(rownorm_kernel, dim3(96), dim3(256), 0, stream, flat, cb, sx, sc);
    hipLaunchKernelGGL(split_kernel,  dim3(6144), dim3(256), 0, stream, flat, cb, xh, xl, ch, cl, count, out);
    hipLaunchKernelGGL(vq_screen_kernel, dim3(256, 2), dim3(512), 0, stream,
                       xh, xl, ch, cl, sc, pm1, pi1, pm2);
    hipLaunchKernelGGL(vq_merge_kernel, dim3(64), dim3(256), 0, stream,
                       pm1, pi1, pm2, out, count, list, qbest);
    hipLaunchKernelGGL(vq_fix_kernel, dim3(16, 64), dim3(256), 0, stream,
                       flat, cb, sx, sc, count, list, qbest);
    hipLaunchKernelGGL(vq_out_kernel, dim3(64), dim3(256), 0, stream, count, list, qbest, out);
}

// Round 22
// 255.117 us; speedup vs baseline: 1.1708x; 1.0586x over previous
//
#include <hip/hip_runtime.h>
#include <float.h>

// r21 config (270 us) + r22 single change: screen codebook repacked into
// MFMA-fragment order pb[group16][frag4][lane64][8bf16] so each wave B-load
// is one contiguous 1KB read (was 64 scattered 128B-stride lines -> L2
// gather-latency bound at 88us, 9x above issue floor).
// Replica-f32 semantics (bit-exact vs np reference) unchanged throughout.
//
// Workspace (float slots). ushort arrays occupy size/2 slots.
//   out1 : ws[0 .. 8388608)
//     xh  = ws+0        ushort[1048576]  -> slots [0,       524288)
//     xl  = ws+524288   ushort[1048576]  -> slots [524288, 1048576)
//     pb  = ws+1048576  ushort[1048576]  -> slots [1048576,1572864)  (packed B)
//     pm1 = ws+1572864  [2][16384] f32
//     pi1 = ws+1605632  [2][16384] i32
//     pm2 = ws+1638400  [2][16384] f32   (ends 1671168 < 8388608)
//   out2 : ws+8388608   [16][64][64][64]
//   flat : ws+12582912  [16384][64]
//   sx   : ws+13631488  [16384]
//   sc   : ws+13647872  [8192]
//   count: ws+13656064  (int)
//   list : ws+13656320  (int[16384])
//   qbest: ws+13672704  (u64[16384] = 32768 slots, ends 13705472)
//   wp2  : ws+13705472  [32768]  packed conv2 weights
//   wp3  : ws+13738240  [65536]  packed conv3 weights (ends 13803776)

#define TAU_ACC 2e-6f   // acc-domain gap threshold (= TAU/2, TAU=4e-6 in g)

typedef __attribute__((ext_vector_type(8))) short s16x8;
typedef __attribute__((ext_vector_type(4))) float f32x4;
typedef unsigned short ushort_t;
typedef unsigned long long u64;

static __device__ __forceinline__ unsigned short f2bf(float f) {
    unsigned u = __float_as_uint(f);
    u = (u + 0x7fffu + ((u >> 16) & 1u)) >> 16;    // RN-even; no NaN in this data
    return (unsigned short)u;
}
static __device__ __forceinline__ float bf2f(unsigned short h) {
    return __uint_as_float(((unsigned)h) << 16);
}

// ---------------- weight repack: w[oc][ic][kh][kw] -> wpack[(ic*16+t)*OC + oc]
__global__ __launch_bounds__(256) void wpack_kernel(const float* __restrict__ w2,
                                                    const float* __restrict__ w3,
                                                    float* __restrict__ wp2,
                                                    float* __restrict__ wp3) {
    int i = blockIdx.x * 256 + threadIdx.x;        // 98304
    if (i < 32768) {                               // w2: [64][32][4][4]
        int oc = i >> 9, rem = i & 511;
        int ic = rem >> 4, t = rem & 15;
        wp2[(ic * 16 + t) * 64 + oc] = w2[i];
    } else if (i < 98304) {                        // w3: [64][64][4][4]
        int j = i - 32768;
        int oc = j >> 10, rem = j & 1023;
        int ic = rem >> 4, t = rem & 15;
        wp3[(ic * 16 + t) * 64 + oc] = w3[j];
    }
}

// ---------------- conv1: x[16,3,256,256] -> relu -> out1[16,32,128,128], k4 s2 p1
__global__ __launch_bounds__(256) void conv1_kernel(const float* __restrict__ in,
                                                    const float* __restrict__ w,   // [32][3][4][4]
                                                    const float* __restrict__ bias,// [32]
                                                    float* __restrict__ out) {
    int p = blockIdx.x * 256 + threadIdx.x;        // 262144
    int ow = p & 127, oh = (p >> 7) & 127, bb = p >> 14;
    int oc0 = blockIdx.y * 16;
    float taps[48];                                 // [ic][kh][kw]
    for (int ic = 0; ic < 3; ++ic) {
        const float* ip = in + (bb * 3 + ic) * 65536;
        #pragma unroll
        for (int kh = 0; kh < 4; ++kh) {
            int ih = oh * 2 - 1 + kh;
            #pragma unroll
            for (int kw = 0; kw < 4; ++kw) {
                int iw = ow * 2 - 1 + kw;
                bool ok = ((unsigned)ih < 256u) && ((unsigned)iw < 256u);
                taps[ic * 16 + kh * 4 + kw] = ok ? ip[ih * 256 + iw] : 0.0f;
            }
        }
    }
    float* op = out + bb * (32 * 16384) + oh * 128 + ow;
    for (int oc = oc0; oc < oc0 + 16; ++oc) {
        float acc = 0.0f;
        const float* wp = w + oc * 48;             // wave-uniform
        #pragma unroll
        for (int t = 0; t < 48; ++t) acc = __fmaf_rn(taps[t], wp[t], acc);
        acc = __fadd_rn(acc, bias[oc]);
        op[oc * 16384] = fmaxf(acc, 0.0f);
    }
}

// ---------------- conv2: 1 row x 16 oc, packed weights (contiguous s_loads)
__global__ __launch_bounds__(256, 4) void conv2_kernel(const float* __restrict__ in,
                                                       const float* __restrict__ wp, // packed [ic*16+t][64]
                                                       const float* __restrict__ bias,
                                                       float* __restrict__ out) {
    int p = blockIdx.x * 256 + threadIdx.x;        // 65536 spatial
    int ow = p & 63, oh = (p >> 6) & 63, bb = p >> 12;   // ow == lane
    int oc0 = blockIdx.y * 16;
    float acc[16];
    #pragma unroll
    for (int j = 0; j < 16; ++j) acc[j] = 0.0f;
    const float* ibase = in + bb * 32 * 16384;

    float r0[4], r1[4];
    #pragma unroll
    for (int kh = 0; kh < 4; ++kh) {               // initial load, ic = 0
        int ih = oh * 2 - 1 + kh;                  // wave-uniform branch
        float v0 = 0.0f, v1 = 0.0f;
        if ((unsigned)ih < 128u) {
            float2 t = *(const float2*)(ibase + ih * 128 + 2 * ow);
            v0 = t.x; v1 = t.y;
        }
        r0[kh] = v0; r1[kh] = v1;
    }
    for (int ic = 0; ic < 32; ++ic) {
        float n0[4], n1[4];                         // prefetch ic+1 (clamped)
        int icn = (ic < 31) ? ic + 1 : 31;
        const float* ipn = ibase + icn * 16384;
        #pragma unroll
        for (int kh = 0; kh < 4; ++kh) {
            int ih = oh * 2 - 1 + kh;
            float v0 = 0.0f, v1 = 0.0f;
            if ((unsigned)ih < 128u) {
                float2 t = *(const float2*)(ipn + ih * 128 + 2 * ow);
                v0 = t.x; v1 = t.y;
            }
            n0[kh] = v0; n1[kh] = v1;
        }
        #pragma unroll
        for (int kh = 0; kh < 4; ++kh) {
            float t0 = __shfl_up(r1[kh], 1);
            if (ow == 0) t0 = 0.0f;                // iw = -1 pad
            float t3 = __shfl_down(r0[kh], 1);
            if (ow == 63) t3 = 0.0f;               // iw = 128 pad
            // packed: kw-group g at wkh[g*64 + j], j=0..15 contiguous
            const float* wkh = wp + (ic * 16 + kh * 4) * 64 + oc0;   // wave-uniform
            #pragma unroll
            for (int j = 0; j < 16; ++j) {
                acc[j] = __fmaf_rn(t0,     wkh[j],       acc[j]);
                acc[j] = __fmaf_rn(r0[kh], wkh[64 + j],  acc[j]);
                acc[j] = __fmaf_rn(r1[kh], wkh[128 + j], acc[j]);
                acc[j] = __fmaf_rn(t3,     wkh[192 + j], acc[j]);
            }
        }
        #pragma unroll
        for (int kh = 0; kh < 4; ++kh) { r0[kh] = n0[kh]; r1[kh] = n1[kh]; }
    }
    float* op = out + bb * (64 * 4096) + oh * 64 + ow;
    #pragma unroll
    for (int j = 0; j < 16; ++j) {
        float y = __fadd_rn(acc[j], bias[oc0 + j]);
        op[(oc0 + j) * 4096] = fmaxf(y, 0.0f);
    }
}

// ---------------- conv3: 1 row x 8 oc, half-wave rows, packed weights
__global__ __launch_bounds__(256) void conv3_kernel(const float* __restrict__ in,
                                                    const float* __restrict__ wp, // packed [ic*16+t][64]
                                                    const float* __restrict__ bias,
                                                    float* __restrict__ flat) {
    int p = blockIdx.x * 256 + threadIdx.x;        // 16384 (== flat row)
    int ow = p & 31, oh = (p >> 5) & 31, bb = p >> 10;   // ow == lane&31
    int oc0 = blockIdx.y * 8;
    float acc[8];
    #pragma unroll
    for (int j = 0; j < 8; ++j) acc[j] = 0.0f;
    const float* ibase = in + bb * 64 * 4096;

    float r0[4], r1[4];
    #pragma unroll
    for (int kh = 0; kh < 4; ++kh) {               // initial load, ic = 0
        int ih = oh * 2 - 1 + kh;
        float v0 = 0.0f, v1 = 0.0f;
        if ((unsigned)ih < 64u) {
            float2 t = *(const float2*)(ibase + ih * 64 + 2 * ow);
            v0 = t.x; v1 = t.y;
        }
        r0[kh] = v0; r1[kh] = v1;
    }
    for (int ic = 0; ic < 64; ++ic) {
        float n0[4], n1[4];                         // prefetch ic+1 (clamped)
        int icn = (ic < 63) ? ic + 1 : 63;
        const float* ipn = ibase + icn * 4096;
        #pragma unroll
        for (int kh = 0; kh < 4; ++kh) {
            int ih = oh * 2 - 1 + kh;
            float v0 = 0.0f, v1 = 0.0f;
            if ((unsigned)ih < 64u) {
                float2 t = *(const float2*)(ipn + ih * 64 + 2 * ow);
                v0 = t.x; v1 = t.y;
            }
            n0[kh] = v0; n1[kh] = v1;
        }
        #pragma unroll
        for (int kh = 0; kh < 4; ++kh) {
            float t0 = __shfl_up(r1[kh], 1);
            if (ow == 0) t0 = 0.0f;                // also kills cross-half garbage
            float t3 = __shfl_down(r0[kh], 1);
            if (ow == 31) t3 = 0.0f;               // also kills cross-half garbage
            const float* wkh = wp + (ic * 16 + kh * 4) * 64 + oc0;   // wave-uniform
            #pragma unroll
            for (int j = 0; j < 8; ++j) {
                acc[j] = __fmaf_rn(t0,     wkh[j],       acc[j]);
                acc[j] = __fmaf_rn(r0[kh], wkh[64 + j],  acc[j]);
                acc[j] = __fmaf_rn(r1[kh], wkh[128 + j], acc[j]);
                acc[j] = __fmaf_rn(t3,     wkh[192 + j], acc[j]);
            }
        }
        #pragma unroll
        for (int kh = 0; kh < 4; ++kh) { r0[kh] = n0[kh]; r1[kh] = n1[kh]; }
    }
    float* op = flat + (size_t)p * 64 + oc0;
    #pragma unroll
    for (int j = 0; j < 8; ++j) {
        float y = __fadd_rn(acc[j], bias[oc0 + j]);
        op[j] = fmaxf(y, 0.0f);
    }
}

// ---------------- row norms: sx[16384], sc[8192] (pairwise-8)
__global__ __launch_bounds__(256) void rownorm_kernel(const float* __restrict__ flat,
                                                      const float* __restrict__ cb,
                                                      float* __restrict__ sx,
                                                      float* __restrict__ sc) {
    int i = blockIdx.x * 256 + threadIdx.x;        // 24576
    const float* src;
    float* dst;
    if (i < 16384) { src = flat + (size_t)i * 64; dst = sx + i; }
    else           { src = cb + (size_t)(i - 16384) * 64; dst = sc + (i - 16384); }
    float r[8];
    #pragma unroll
    for (int j = 0; j < 8; ++j) r[j] = __fmul_rn(src[j], src[j]);
    #pragma unroll
    for (int b = 1; b < 8; ++b)
        #pragma unroll
        for (int j = 0; j < 8; ++j)
            r[j] = __fadd_rn(r[j], __fmul_rn(src[b * 8 + j], src[b * 8 + j]));
    float s01 = __fadd_rn(r[0], r[1]), s23 = __fadd_rn(r[2], r[3]);
    float s45 = __fadd_rn(r[4], r[5]), s67 = __fadd_rn(r[6], r[7]);
    *dst = __fadd_rn(__fadd_rn(s01, s23), __fadd_rn(s45, s67));
}

// ---------------- split: f32 -> bf16 hi/lo.
// x -> xh/xl linear; codebook -> pb in MFMA-fragment order:
//   pb[group(=k>>4)*2048 + frag*512 + ((lk*16+le))*8 + e]
//   frag: 0=hi d<32, 1=hi d>=32, 2=lo d<32, 3=lo d>=32; lk=(d&31)>>3, e=d&7, le=k&15
__global__ __launch_bounds__(256) void split_kernel(const float* __restrict__ flat,
                                                    const float* __restrict__ cb,
                                                    ushort_t* __restrict__ xh,
                                                    ushort_t* __restrict__ xl,
                                                    ushort_t* __restrict__ pb,
                                                    int* __restrict__ count,
                                                    float* __restrict__ out) {
    int i = blockIdx.x * 256 + threadIdx.x;        // 1572864
    if (i == 0) { *count = 0; out[16384] = 0.0f; }
    if (i < 1048576) {
        float v = flat[i];
        unsigned short h = f2bf(v);
        xh[i] = h;
        xl[i] = f2bf(v - bf2f(h));
    } else {
        int j = i - 1048576;                       // 0..524287
        int k = j >> 6, d = j & 63;
        float v = cb[j];
        unsigned short h = f2bf(v);
        unsigned short l = f2bf(v - bf2f(h));
        int g = k >> 4, le = k & 15;
        int hf = d >> 5, lk = (d >> 3) & 3, e = d & 7;
        size_t base = (size_t)g * 2048 + ((lk << 4) | le) * 8 + e;
        pb[base + hf * 512] = h;
        pb[base + (2 + hf) * 512] = l;
    }
}

// ---------------- MFMA screen: 256 row-blocks x 2 code-halves; 4096 codes each.
// acc init = -sc/2 -> argmin(g) == argmax(acc). Ping-pong fragment-packed B:
// one wave B-load = 4 x contiguous 1KB (frag-major), fully coalesced.
#define SCREEN_LOAD(BH0, BH1, BL0, BL1, SCV, GRP)                         \
    {                                                                     \
        const ushort_t* pb_ = pb + ((size_t)((GRP) >> 4) * 2048) + lane * 8; \
        BH0 = *(const s16x8*)(pb_);                                       \
        BH1 = *(const s16x8*)(pb_ + 512);                                 \
        BL0 = *(const s16x8*)(pb_ + 1024);                                \
        BL1 = *(const s16x8*)(pb_ + 1536);                                \
        SCV = sc[(GRP) + le];                                             \
    }

#define SCREEN_COMPUTE(BH0, BH1, BL0, BL1, SCV, COL)                      \
    {                                                                     \
        float ini_ = __fmul_rn(-0.5f, SCV);                               \
        f32x4 acc[4];                                                     \
        _Pragma("unroll")                                                 \
        for (int i = 0; i < 4; ++i) acc[i] = (f32x4){ini_, ini_, ini_, ini_}; \
        _Pragma("unroll")                                                 \
        for (int i = 0; i < 4; ++i) acc[i] = __builtin_amdgcn_mfma_f32_16x16x32_bf16(a[i][0], BH0, acc[i], 0, 0, 0); \
        _Pragma("unroll")                                                 \
        for (int i = 0; i < 4; ++i) acc[i] = __builtin_amdgcn_mfma_f32_16x16x32_bf16(a[i][1], BH1, acc[i], 0, 0, 0); \
        _Pragma("unroll")                                                 \
        for (int i = 0; i < 4; ++i) acc[i] = __builtin_amdgcn_mfma_f32_16x16x32_bf16(a[i][0], BL0, acc[i], 0, 0, 0); \
        _Pragma("unroll")                                                 \
        for (int i = 0; i < 4; ++i) acc[i] = __builtin_amdgcn_mfma_f32_16x16x32_bf16(a[i][1], BL1, acc[i], 0, 0, 0); \
        _Pragma("unroll")                                                 \
        for (int i = 0; i < 4; ++i) acc[i] = __builtin_amdgcn_mfma_f32_16x16x32_bf16(a[i][2], BH0, acc[i], 0, 0, 0); \
        _Pragma("unroll")                                                 \
        for (int i = 0; i < 4; ++i) acc[i] = __builtin_amdgcn_mfma_f32_16x16x32_bf16(a[i][3], BH1, acc[i], 0, 0, 0); \
        _Pragma("unroll")                                                 \
        for (int i = 0; i < 4; ++i) {                                     \
            _Pragma("unroll")                                             \
            for (int reg = 0; reg < 4; ++reg) {                           \
                int s_ = i * 4 + reg;                                     \
                float av_ = acc[i][reg];                                  \
                m2[s_] = __builtin_amdgcn_fmed3f(m1[s_], m2[s_], av_);    \
                i1[s_] = (av_ > m1[s_]) ? (COL) : i1[s_];                 \
                m1[s_] = fmaxf(m1[s_], av_);                              \
            }                                                             \
        }                                                                 \
    }

__global__ __launch_bounds__(512, 2) void vq_screen_kernel(const ushort_t* __restrict__ xh,
                                                           const ushort_t* __restrict__ xl,
                                                           const ushort_t* __restrict__ pb,
                                                           const float* __restrict__ sc,
                                                           float* __restrict__ pm1,   // [2][16384]
                                                           int* __restrict__ pi1,
                                                           float* __restrict__ pm2) {
    __shared__ float lm1[8][64];
    __shared__ int   li1[8][64];
    __shared__ float lm2[8][64];
    int tid = threadIdx.x;
    int row0 = blockIdx.x * 64;
    int half = blockIdx.y;
    int kbase = half * 4096;
    int w = tid >> 6, lane = tid & 63;
    int le = lane & 15, lk = lane >> 4;

    // A fragments in registers (reused across all codes) — kept resident
    s16x8 a[4][4];
    #pragma unroll
    for (int i = 0; i < 4; ++i) {
        size_t ar = (size_t)(row0 + i * 16 + le) * 64 + lk * 8;
        a[i][0] = *(const s16x8*)(xh + ar);
        a[i][1] = *(const s16x8*)(xh + ar + 32);
        a[i][2] = *(const s16x8*)(xl + ar);
        a[i][3] = *(const s16x8*)(xl + ar + 32);
    }

    float m1[16], m2[16];
    int i1[16];
    #pragma unroll
    for (int s = 0; s < 16; ++s) { m1[s] = -FLT_MAX; m2[s] = -FLT_MAX; i1[s] = 0x7fffffff; }

    int grp0 = kbase + w * 16;                     // group base (no le)

    s16x8 b0h0, b0h1, b0l0, b0l1, b1h0, b1h1, b1l0, b1l1;
    float sc0, sc1;
    SCREEN_LOAD(b0h0, b0h1, b0l0, b0l1, sc0, grp0);         // nb = 0

    for (int nbp = 0; nbp < 16; ++nbp) {
        int gA = grp0 + nbp * 256;                           // nb = 2*nbp
        int gB = gA + 128;                                   // nb = 2*nbp+1
        int gN = (nbp < 15) ? gA + 256 : grp0;               // wrap: redundant, unused
        SCREEN_LOAD(b1h0, b1h1, b1l0, b1l1, sc1, gB);
        SCREEN_COMPUTE(b0h0, b0h1, b0l0, b0l1, sc0, gA + le);
        SCREEN_LOAD(b0h0, b0h1, b0l0, b0l1, sc0, gN);
        SCREEN_COMPUTE(b1h0, b1h1, b1l0, b1l1, sc1, gB + le);
    }

    // merge across the 16 le-lanes (max domain)
    #pragma unroll
    for (int i = 0; i < 4; ++i) {
        #pragma unroll
        for (int reg = 0; reg < 4; ++reg) {
            int s = i * 4 + reg;
            float v1 = m1[s], v2 = m2[s];
            int ix = i1[s];
            #pragma unroll
            for (int mask = 1; mask < 16; mask <<= 1) {
                float o1 = __shfl_xor(v1, mask);
                int oi = __shfl_xor(ix, mask);
                float o2 = __shfl_xor(v2, mask);
                float n2 = fmaxf(fmaxf(v2, o2), fminf(v1, o1));
                ix = (o1 > v1) ? oi : ((o1 == v1 && oi < ix) ? oi : ix);
                v1 = fmaxf(v1, o1);
                v2 = n2;
            }
            if (le == 0) {
                int rl = i * 16 + lk * 4 + reg;
                lm1[w][rl] = v1; li1[w][rl] = ix; lm2[w][rl] = v2;
            }
        }
    }
    __syncthreads();
    if (tid < 64) {
        float M1 = -FLT_MAX, M2 = -FLT_MAX;
        int I1 = 0x7fffffff;
        #pragma unroll
        for (int ww = 0; ww < 8; ++ww) {
            float a1 = lm1[ww][tid], a2 = lm2[ww][tid];
            int ai = li1[ww][tid];
            M2 = fmaxf(fmaxf(M2, a2), fminf(M1, a1));
            if (a1 > M1 || (a1 == M1 && ai < I1)) I1 = ai;
            M1 = fmaxf(M1, a1);
        }
        size_t o = (size_t)half * 16384 + row0 + tid;   // row-major, coalesced
        pm1[o] = M1; pi1[o] = I1; pm2[o] = M2;
    }
}

// ---------------- merge: combine 2 halves (max domain), gap test, out or flag
__global__ __launch_bounds__(256) void vq_merge_kernel(const float* __restrict__ pm1,
                                                       const int* __restrict__ pi1,
                                                       const float* __restrict__ pm2,
                                                       float* __restrict__ out,
                                                       int* __restrict__ count,
                                                       int* __restrict__ list,
                                                       u64* __restrict__ qbest) {
    int row = blockIdx.x * 256 + threadIdx.x;      // 16384
    float a1 = pm1[row], b1 = pm1[16384 + row];
    int ai = pi1[row], bi = pi1[16384 + row];
    float a2 = pm2[row], b2 = pm2[16384 + row];
    float M1 = fmaxf(a1, b1);
    int I1 = (b1 > a1) ? bi : ai;                  // tie -> ai (half-0 has lower idx)
    float M2 = fmaxf(fmaxf(a2, b2), fminf(a1, b1));
    if (M1 - M2 >= TAU_ACC) {
        out[row] = (float)I1;                      // provably the replica argmin
    } else {
        qbest[row] = 0xFFFFFFFFFFFFFFFFull;
        int pos = atomicAdd(count, 1);
        list[pos] = row;
    }
}

// ---------------- fix: coalesced exact replica recompute of flagged rows.
// grid (16 rowchunk-strides, 64 codetiles); block = 64 rows x 128 codes.
#define FLDP 68
__global__ __launch_bounds__(256) void vq_fix_kernel(const float* __restrict__ flat,
                                                     const float* __restrict__ cb,
                                                     const float* __restrict__ sx,
                                                     const float* __restrict__ sc,
                                                     const int* __restrict__ count,
                                                     const int* __restrict__ list,
                                                     u64* __restrict__ qbest) {
    __shared__ float xs[64 * FLDP];
    __shared__ float cs[128 * FLDP];
    __shared__ float sxs[64], scs[128];
    __shared__ int rowids[64];
    int n = *count;
    int cb0 = blockIdx.y * 128;
    int tid = threadIdx.x;

    for (int rb = blockIdx.x; rb * 64 < n; rb += 16) {
        int nrows = n - rb * 64; if (nrows > 64) nrows = 64;

        // stage rows (gather) + sx + rowids
        #pragma unroll
        for (int s = 0; s < 4; ++s) {
            int idx = tid + 256 * s;               // 1024 float4s
            int r = idx >> 4, c = idx & 15;
            int rr = rb * 64 + r; if (rr >= n) rr = n - 1;
            int row = list[rr];
            if (c == 0) { rowids[r] = row; sxs[r] = sx[row]; }
            *(float4*)&xs[r * FLDP + c * 4] = *(const float4*)(flat + (size_t)row * 64 + c * 4);
        }
        // stage codes (coalesced)
        #pragma unroll
        for (int s = 0; s < 8; ++s) {
            int idx = tid + 256 * s;               // 2048 float4s
            int r = idx >> 4, c = idx & 15;
            *(float4*)&cs[r * FLDP + c * 4] = *(const float4*)(cb + (size_t)(cb0 + r) * 64 + c * 4);
        }
        if (tid < 128) scs[tid] = sc[cb0 + tid];
        __syncthreads();

        int tr = tid >> 4, tc = tid & 15;          // rows tr+16i (i<4), codes tc+16j (j<8)
        float acc[4][8];
        #pragma unroll
        for (int i = 0; i < 4; ++i)
            #pragma unroll
            for (int j = 0; j < 8; ++j) acc[i][j] = 0.0f;

        for (int d = 0; d < 64; d += 4) {          // strictly ascending d: replica chain
            float4 ax[4], bc[8];
            #pragma unroll
            for (int i = 0; i < 4; ++i) ax[i] = *(const float4*)&xs[(tr + 16 * i) * FLDP + d];
            #pragma unroll
            for (int j = 0; j < 8; ++j) bc[j] = *(const float4*)&cs[(tc + 16 * j) * FLDP + d];
            #pragma unroll
            for (int i = 0; i < 4; ++i)
                #pragma unroll
                for (int j = 0; j < 8; ++j) {
                    acc[i][j] = __fmaf_rn(ax[i].x, bc[j].x, acc[i][j]);
                    acc[i][j] = __fmaf_rn(ax[i].y, bc[j].y, acc[i][j]);
                    acc[i][j] = __fmaf_rn(ax[i].z, bc[j].z, acc[i][j]);
                    acc[i][j] = __fmaf_rn(ax[i].w, bc[j].w, acc[i][j]);
                }
        }

        float best[4];
        int bidx[4];
        #pragma unroll
        for (int i = 0; i < 4; ++i) { best[i] = FLT_MAX; bidx[i] = 0x7fffffff; }
        #pragma unroll
        for (int j = 0; j < 8; ++j) {              // ascending k within lane
            int k = cb0 + tc + 16 * j;
            float scj = scs[tc + 16 * j];
            #pragma unroll
            for (int i = 0; i < 4; ++i) {
                float t1 = __fadd_rn(sxs[tr + 16 * i], scj);
                float q = __fmaf_rn(-2.0f, acc[i][j], t1);   // replica q
                if (q < best[i]) { best[i] = q; bidx[i] = k; }
            }
        }

        // per-row merge across tc (reuse cs)
        __syncthreads();
        float* rmin = cs;                          // [64][16]
        int* ridx = (int*)(cs + 1024);             // [64][16]
        #pragma unroll
        for (int i = 0; i < 4; ++i) {
            rmin[(tr + 16 * i) * 16 + tc] = best[i];
            ridx[(tr + 16 * i) * 16 + tc] = bidx[i];
        }
        __syncthreads();
        if (tid < nrows) {
            float m = FLT_MAX; int mi = 0x7fffffff;
            for (int t2 = 0; t2 < 16; ++t2) {
                float v = rmin[tid * 16 + t2];
                int ix = ridx[tid * 16 + t2];
                if (v < m || (v == m && ix < mi)) { m = v; mi = ix; }
            }
            u64 key = ((u64)__float_as_uint(m) << 32) | (unsigned)mi;  // q>0 -> order ok
            atomicMin(&qbest[rowids[tid]], key);
        }
        __syncthreads();                           // cs/xs reuse safe for next rb
    }
}

// ---------------- vq_out: write flagged rows from qbest
__global__ __launch_bounds__(256) void vq_out_kernel(const int* __restrict__ count,
                                                     const int* __restrict__ list,
                                                     const u64* __restrict__ qbest,
                                                     float* __restrict__ out) {
    int pos = blockIdx.x * 256 + threadIdx.x;      // 16384
    if (pos >= *count) return;
    int row = list[pos];
    out[row] = (float)(unsigned)(qbest[row] & 0xffffffffull);
}

extern "C" void kernel_launch(void* const* d_in, const int* in_sizes, int n_in,
                              void* d_out, int out_size, void* d_ws, size_t ws_size,
                              hipStream_t stream) {
    const float* x  = (const float*)d_in[0];
    const float* w1 = (const float*)d_in[1];
    const float* b1 = (const float*)d_in[2];
    const float* w2 = (const float*)d_in[3];
    const float* b2 = (const float*)d_in[4];
    const float* w3 = (const float*)d_in[5];
    const float* b3 = (const float*)d_in[6];
    const float* cb = (const float*)d_in[7];

    float* ws   = (float*)d_ws;
    float* out1 = ws;                               // [0, 8388608)
    ushort_t* xh = (ushort_t*)(ws + 0);             // aliases out1 (post-conv2)
    ushort_t* xl = (ushort_t*)(ws + 524288);
    ushort_t* pb = (ushort_t*)(ws + 1048576);       // packed B, slots [1048576,1572864)
    float* pm1  = ws + 1572864;                     // [2][16384]
    int*   pi1  = (int*)(ws + 1605632);
    float* pm2  = ws + 1638400;                     // ends 1671168 < 8388608
    float* out2 = ws + 8388608;
    float* flat = ws + 12582912;
    float* sx   = ws + 13631488;
    float* sc   = ws + 13647872;
    int*   count = (int*)(ws + 13656064);
    int*   list  = (int*)(ws + 13656320);
    u64*   qbest = (u64*)(ws + 13672704);           // 32768 slots, ends 13705472
    float* wp2  = ws + 13705472;                    // [32768]
    float* wp3  = ws + 13738240;                    // [65536], ends 13803776
    float* out  = (float*)d_out;

    hipLaunchKernelGGL(wpack_kernel,  dim3(384), dim3(256), 0, stream, w2, w3, wp2, wp3);
    hipLaunchKernelGGL(conv1_kernel,  dim3(1024, 2), dim3(256), 0, stream, x, w1, b1, out1);
    hipLaunchKernelGGL(conv2_kernel,  dim3(256, 4), dim3(256), 0, stream, out1, wp2, b2, out2);
    hipLaunchKernelGGL(conv3_kernel,  dim3(64, 8), dim3(256), 0, stream, out2, wp3, b3, flat);
    hipLaunchKernelGGL(rownorm_kernel, dim3(96), dim3(256), 0, stream, flat, cb, sx, sc);
    hipLaunchKernelGGL(split_kernel,  dim3(6144), dim3(256), 0, stream, flat, cb, xh, xl, pb, count, out);
    hipLaunchKernelGGL(vq_screen_kernel, dim3(256, 2), dim3(512), 0, stream,
                       xh, xl, pb, sc, pm1, pi1, pm2);
    hipLaunchKernelGGL(vq_merge_kernel, dim3(64), dim3(256), 0, stream,
                       pm1, pi1, pm2, out, count, list, qbest);
    hipLaunchKernelGGL(vq_fix_kernel, dim3(16, 64), dim3(256), 0, stream,
                       flat, cb, sx, sc, count, list, qbest);
    hipLaunchKernelGGL(vq_out_kernel, dim3(64), dim3(256), 0, stream, count, list, qbest, out);
}